// Round 2
// baseline (376.456 us; speedup 1.0000x reference)
//
#include <hip/hip_runtime.h>

#define IMG   512
#define NIMG  32
#define TX    64
#define TY    32
#define HALF  16               /* rows per half-pass */
#define HROWS 42               /* TY + 10 staged input rows */
#define AQ    20               /* input quads/row (80 floats, col offset -8) */
#define VQ    21               /* sV quads/row (20 used + 1 pad, stride 21%8=5) */
#define NPIX  (32.0f * 512.0f * 512.0f)

constexpr float GW[11] = {
    0.00102838f, 0.00759876f, 0.03600077f, 0.10936069f, 0.21300553f,
    0.26601174f,
    0.21300553f, 0.10936069f, 0.03600077f, 0.00759876f, 0.00102838f
};
constexpr float C1c = 0.0001f;
constexpr float C2c = 0.0009f;

__global__ void ssim_init_out(float* __restrict__ out) { out[0] = 1.0f; }

__device__ __forceinline__ float4 f4mul(float4 a, float4 b) {
    return make_float4(a.x * b.x, a.y * b.y, a.z * b.z, a.w * b.w);
}
__device__ __forceinline__ float4 f4fma(float w, float4 v, float4 c) {
    return make_float4(fmaf(w, v.x, c.x), fmaf(w, v.y, c.y),
                       fmaf(w, v.z, c.z), fmaf(w, v.w, c.w));
}

// 11-tap horizontal conv producing 8 outputs from 6 LDS quads (24 floats).
// row points at an sV row (float4 units); qb = 2*t. Output col x=8t+e needs
// float indices e+3 .. e+13 within the 24 loaded.
__device__ __forceinline__ void hconv8(const float4* __restrict__ row, int qb,
                                       float out[8]) {
    float4 va[6];
#pragma unroll
    for (int d = 0; d < 6; ++d) va[d] = row[qb + d];
    float v[24];
#pragma unroll
    for (int d = 0; d < 6; ++d) {
        v[4 * d + 0] = va[d].x; v[4 * d + 1] = va[d].y;
        v[4 * d + 2] = va[d].z; v[4 * d + 3] = va[d].w;
    }
#pragma unroll
    for (int e = 0; e < 8; ++e) {
        float s = GW[0] * v[e + 3];
#pragma unroll
        for (int k = 1; k < 11; ++k) s = fmaf(GW[k], v[e + 3 + k], s);
        out[e] = s;
    }
}

__global__ __launch_bounds__(256, 3) void ssim_fused(
        const float* __restrict__ img1, const float* __restrict__ img2,
        float* __restrict__ out) {
    // LDS: 840*16*2 + 1680*16 = 53760 B -> 3 blocks/CU
    __shared__ float4 sA4[HROWS * AQ];        // [42][20]
    __shared__ float4 sB4[HROWS * AQ];
    __shared__ float4 sV4[5 * HALF * VQ];     // [ch][16][21]

    const int tid = threadIdx.x;
    const int X0 = blockIdx.x * TX;
    const int Y0 = blockIdx.y * TY;
    const int n  = blockIdx.z;
    const float* a0 = img1 + (size_t)n * IMG * IMG;
    const float* b0 = img2 + (size_t)n * IMG * IMG;

    // ---- stage 42 rows x 80 cols of both images (zero halo), float4 ----
    // col c <-> gx = X0 - 8 + c  (16B-aligned global quads)
    for (int i = tid; i < 2 * HROWS * AQ; i += 256) {
        int j = i;
        const float* src = a0;
        float4* dst = sA4;
        if (j >= HROWS * AQ) { j -= HROWS * AQ; src = b0; dst = sB4; }
        int r = j / AQ;
        int q = j - r * AQ;
        int gy  = Y0 - 5 + r;
        int gx0 = X0 - 8 + q * 4;
        float4 val;
        if ((unsigned)gy < IMG && gx0 >= 0 && gx0 + 3 < IMG) {
            val = *(const float4*)(src + gy * IMG + gx0);
        } else {
            float tmp[4];
#pragma unroll
            for (int t2 = 0; t2 < 4; ++t2) {
                int gx = gx0 + t2;
                bool ok = ((unsigned)gy < IMG) && ((unsigned)gx < IMG);
                tmp[t2] = ok ? src[gy * IMG + gx] : 0.0f;
            }
            val = make_float4(tmp[0], tmp[1], tmp[2], tmp[3]);
        }
        dst[j] = val;
    }
    __syncthreads();

    float sum = 0.0f;

    for (int h = 0; h < 2; ++h) {
        // ---- vertical pass: 5 channels, 4 output rows per thread ----
        // item: q in [0,20), rg in [0,4); out rows y = h*16 + 4rg + o
        if (tid < 80) {
            int q  = tid % 20;
            int rg = tid / 20;
            int rbase = h * HALF + rg * 4;          // sA row for k=0
            float4 acc[5][4];
#pragma unroll
            for (int ch = 0; ch < 5; ++ch)
#pragma unroll
                for (int o = 0; o < 4; ++o)
                    acc[ch][o] = make_float4(0.f, 0.f, 0.f, 0.f);
#pragma unroll
            for (int k = 0; k < 14; ++k) {
                float4 a = sA4[(rbase + k) * AQ + q];
                float4 b = sB4[(rbase + k) * AQ + q];
                float4 aa = f4mul(a, a);
                float4 bb = f4mul(b, b);
                float4 ab = f4mul(a, b);
#pragma unroll
                for (int o = 0; o < 4; ++o) {
                    int j = k - o;
                    if (j >= 0 && j < 11) {
                        float w = GW[j];
                        acc[0][o] = f4fma(w, a,  acc[0][o]);
                        acc[1][o] = f4fma(w, b,  acc[1][o]);
                        acc[2][o] = f4fma(w, aa, acc[2][o]);
                        acc[3][o] = f4fma(w, bb, acc[3][o]);
                        acc[4][o] = f4fma(w, ab, acc[4][o]);
                    }
                }
            }
#pragma unroll
            for (int o = 0; o < 4; ++o) {
                int yl = rg * 4 + o;                // local row in half
#pragma unroll
                for (int ch = 0; ch < 5; ++ch)
                    sV4[ch * (HALF * VQ) + yl * VQ + q] = acc[ch][o];
            }
        }
        __syncthreads();

        // ---- horizontal pass + ssim: 8 outputs per thread ----
        if (tid < 128) {
            int yl = tid >> 3;          // 0..15
            int t  = tid & 7;           // out cols 8t..8t+7
            float mu1[8], mu2[8], x11[8], x22[8], x12[8];
            hconv8(&sV4[0 * (HALF * VQ) + yl * VQ], 2 * t, mu1);
            hconv8(&sV4[1 * (HALF * VQ) + yl * VQ], 2 * t, mu2);
            hconv8(&sV4[2 * (HALF * VQ) + yl * VQ], 2 * t, x11);
            hconv8(&sV4[3 * (HALF * VQ) + yl * VQ], 2 * t, x22);
            hconv8(&sV4[4 * (HALF * VQ) + yl * VQ], 2 * t, x12);
#pragma unroll
            for (int e = 0; e < 8; ++e) {
                float m1s = mu1[e] * mu1[e];
                float m2s = mu2[e] * mu2[e];
                float m12 = mu1[e] * mu2[e];
                float s1  = x11[e] - m1s;
                float s2  = x22[e] - m2s;
                float s12 = x12[e] - m12;
                float num = (2.0f * m12 + C1c) * (2.0f * s12 + C2c);
                float den = (m1s + m2s + C1c) * (s1 + s2 + C2c);
                sum += num / den;
            }
        }
        __syncthreads();   // protect sV before next half overwrites
    }

    // ---- block reduction ----
#pragma unroll
    for (int off = 32; off > 0; off >>= 1)
        sum += __shfl_down(sum, off, 64);

    __shared__ float wred[4];
    if ((tid & 63) == 0) wred[tid >> 6] = sum;
    __syncthreads();
    if (tid == 0) {
        float s = wred[0] + wred[1] + wred[2] + wred[3];
        atomicAdd(out, -s * (1.0f / NPIX));
    }
}

extern "C" void kernel_launch(void* const* d_in, const int* in_sizes, int n_in,
                              void* d_out, int out_size, void* d_ws, size_t ws_size,
                              hipStream_t stream) {
    const float* img1 = (const float*)d_in[0];
    const float* img2 = (const float*)d_in[1];
    float* out = (float*)d_out;

    ssim_init_out<<<1, 1, 0, stream>>>(out);

    dim3 grid(IMG / TX, IMG / TY, NIMG);   // 8 x 16 x 32 = 4096 blocks
    ssim_fused<<<grid, 256, 0, stream>>>(img1, img2, out);
}

// Round 3
// 195.648 us; speedup vs baseline: 1.9241x; 1.9241x over previous
//
#include <hip/hip_runtime.h>

#define IMG   512
#define NIMG  32
#define TX    64
#define TY    16
#define SROWS 26          /* TY + 10 staged input rows */
#define SQ    20          /* data quads per staged row (80 floats, col offset -8) */
#define AST   21          /* staged row stride in quads (pad -> conflict-free) */
#define VQ    21          /* sV row stride in quads (20 data + 1 pad) */
#define NPIX  (32.0f * 512.0f * 512.0f)

constexpr float GW[11] = {
    0.00102838f, 0.00759876f, 0.03600077f, 0.10936069f, 0.21300553f,
    0.26601174f,
    0.21300553f, 0.10936069f, 0.03600077f, 0.00759876f, 0.00102838f
};
constexpr float C1c = 0.0001f;
constexpr float C2c = 0.0009f;

__global__ void ssim_init_out(float* __restrict__ out) { out[0] = 1.0f; }

__device__ __forceinline__ float4 f4mul(float4 a, float4 b) {
    return make_float4(a.x * b.x, a.y * b.y, a.z * b.z, a.w * b.w);
}
__device__ __forceinline__ float4 f4fma(float w, float4 v, float4 c) {
    return make_float4(fmaf(w, v.x, c.x), fmaf(w, v.y, c.y),
                       fmaf(w, v.z, c.z), fmaf(w, v.w, c.w));
}

__global__ __launch_bounds__(256) void ssim_fused(
        const float* __restrict__ img1, const float* __restrict__ img2,
        float* __restrict__ out) {
    // LDS: 2*546*16 + 1680*16 = 44352 B -> 3 blocks/CU
    __shared__ float4 sA4[SROWS * AST];
    __shared__ float4 sB4[SROWS * AST];
    __shared__ float4 sV4[5 * TY * VQ];   // [ch][16][21]

    const int tid = threadIdx.x;
    const int X0 = blockIdx.x * TX;
    const int Y0 = blockIdx.y * TY;
    const int n  = blockIdx.z;
    const float* a0 = img1 + (size_t)n * IMG * IMG;
    const float* b0 = img2 + (size_t)n * IMG * IMG;

    // ---- stage 26 rows x 80 cols of both images (zero halo), float4 ----
    // staged col c_b <-> gx = X0 - 8 + c_b  (16B-aligned global quads)
    for (int i = tid; i < 2 * SROWS * SQ; i += 256) {
        int j = i;
        const float* src = a0;
        float4* dst = sA4;
        if (j >= SROWS * SQ) { j -= SROWS * SQ; src = b0; dst = sB4; }
        int r = j / SQ;
        int q = j - r * SQ;
        int gy  = Y0 - 5 + r;
        int gx0 = X0 - 8 + q * 4;
        float4 val;
        if ((unsigned)gy < IMG && gx0 >= 0 && gx0 + 3 < IMG) {
            val = *(const float4*)(src + gy * IMG + gx0);
        } else {
            float tmp[4];
#pragma unroll
            for (int t2 = 0; t2 < 4; ++t2) {
                int gx = gx0 + t2;
                bool ok = ((unsigned)gy < IMG) && ((unsigned)gx < IMG);
                tmp[t2] = ok ? src[gy * IMG + gx] : 0.0f;
            }
            val = make_float4(tmp[0], tmp[1], tmp[2], tmp[3]);
        }
        dst[r * AST + q] = val;
    }
    __syncthreads();

    // ---- vertical pass: 5 channels on the fly, 2 output rows per thread ----
    // items: q in [0,20) x row-pair g in [0,8) -> 160 threads
    if (tid < 160) {
        int q = tid % 20;
        int g = tid / 20;
        int y0 = 2 * g;                    // first output row of the pair
        float4 acc[5][2];
#pragma unroll
        for (int ch = 0; ch < 5; ++ch)
#pragma unroll
            for (int o = 0; o < 2; ++o)
                acc[ch][o] = make_float4(0.f, 0.f, 0.f, 0.f);
#pragma unroll
        for (int k = 0; k < 12; ++k) {
            float4 a = sA4[(y0 + k) * AST + q];
            float4 b = sB4[(y0 + k) * AST + q];
            float4 aa = f4mul(a, a);
            float4 bb = f4mul(b, b);
            float4 ab = f4mul(a, b);
            if (k <= 10) {
                float w = GW[k];
                acc[0][0] = f4fma(w, a,  acc[0][0]);
                acc[1][0] = f4fma(w, b,  acc[1][0]);
                acc[2][0] = f4fma(w, aa, acc[2][0]);
                acc[3][0] = f4fma(w, bb, acc[3][0]);
                acc[4][0] = f4fma(w, ab, acc[4][0]);
            }
            if (k >= 1) {
                float w = GW[k - 1];
                acc[0][1] = f4fma(w, a,  acc[0][1]);
                acc[1][1] = f4fma(w, b,  acc[1][1]);
                acc[2][1] = f4fma(w, aa, acc[2][1]);
                acc[3][1] = f4fma(w, bb, acc[3][1]);
                acc[4][1] = f4fma(w, ab, acc[4][1]);
            }
        }
#pragma unroll
        for (int o = 0; o < 2; ++o)
#pragma unroll
            for (int ch = 0; ch < 5; ++ch)
                sV4[ch * (TY * VQ) + (y0 + o) * VQ + q] = acc[ch][o];
    }
    __syncthreads();

    // ---- horizontal pass + ssim: 4 output cols per thread, 256 items ----
    float sum = 0.0f;
    {
        int y = tid >> 4;           // 0..15
        int c = tid & 15;           // output quad 0..15 (cols 4c..4c+3)
        float4 res[5];
#pragma unroll
        for (int ch = 0; ch < 5; ++ch) {
            const float4* row = &sV4[ch * (TY * VQ) + y * VQ];
            float v[20];
#pragma unroll
            for (int d = 0; d < 5; ++d) {
                float4 t = row[c + d];
                v[4 * d + 0] = t.x; v[4 * d + 1] = t.y;
                v[4 * d + 2] = t.z; v[4 * d + 3] = t.w;
            }
            // out col 4c+e needs v[e+3 .. e+13]
            float r[4];
#pragma unroll
            for (int e = 0; e < 4; ++e) {
                float s = GW[0] * v[e + 3];
#pragma unroll
                for (int k = 1; k < 11; ++k) s = fmaf(GW[k], v[e + 3 + k], s);
                r[e] = s;
            }
            res[ch] = make_float4(r[0], r[1], r[2], r[3]);
        }
        const float* mu1 = (const float*)&res[0];
        const float* mu2 = (const float*)&res[1];
        const float* x11 = (const float*)&res[2];
        const float* x22 = (const float*)&res[3];
        const float* x12 = (const float*)&res[4];
#pragma unroll
        for (int e = 0; e < 4; ++e) {
            float m1s = mu1[e] * mu1[e];
            float m2s = mu2[e] * mu2[e];
            float m12 = mu1[e] * mu2[e];
            float s1  = x11[e] - m1s;
            float s2  = x22[e] - m2s;
            float s12 = x12[e] - m12;
            float num = (2.0f * m12 + C1c) * (2.0f * s12 + C2c);
            float den = (m1s + m2s + C1c) * (s1 + s2 + C2c);
            sum += num / den;
        }
    }

    // ---- block reduction ----
#pragma unroll
    for (int off = 32; off > 0; off >>= 1)
        sum += __shfl_down(sum, off, 64);

    __shared__ float wred[4];
    if ((tid & 63) == 0) wred[tid >> 6] = sum;
    __syncthreads();
    if (tid == 0) {
        float s = wred[0] + wred[1] + wred[2] + wred[3];
        atomicAdd(out, -s * (1.0f / NPIX));
    }
}

extern "C" void kernel_launch(void* const* d_in, const int* in_sizes, int n_in,
                              void* d_out, int out_size, void* d_ws, size_t ws_size,
                              hipStream_t stream) {
    const float* img1 = (const float*)d_in[0];
    const float* img2 = (const float*)d_in[1];
    float* out = (float*)d_out;

    ssim_init_out<<<1, 1, 0, stream>>>(out);

    dim3 grid(IMG / TX, IMG / TY, NIMG);   // 8 x 32 x 32 = 8192 blocks
    ssim_fused<<<grid, 256, 0, stream>>>(img1, img2, out);
}